// Round 1
// baseline (388.698 us; speedup 1.0000x reference)
//
#include <hip/hip_runtime.h>
#include <hip/hip_bf16.h>
#include <cstdint>

#define NHEAD 16
#define HDIM 64
#define ORDERS 4

typedef short short8 __attribute__((ext_vector_type(8)));
typedef float f32x4 __attribute__((ext_vector_type(4)));

__device__ __forceinline__ unsigned short f32_to_bf16_rtn(float f) {
  union { float f; unsigned u; } v; v.f = f;
  unsigned r = v.u + 0x7FFFu + ((v.u >> 16) & 1u);
  return (unsigned short)(r >> 16);
}

// ---------------- Kernel 1: M_h = sum_{k=0..4} (t A_h)^k / k! ----------------
__global__ void compute_M_kernel(const float* __restrict__ A,
                                 const float* __restrict__ t_ptr,
                                 float* __restrict__ M_all) {
  __shared__ float Ah[64 * 64];
  __shared__ float T[64 * 64];
  __shared__ float Tn[64 * 64];
  __shared__ float Ms[64 * 64];
  const int h = blockIdx.x;
  const int tid = threadIdx.x;
  const float t = t_ptr[0];
  for (int r = 0; r < 16; ++r) {
    int idx = tid + 256 * r;
    Ah[idx] = A[h * 4096 + idx];
    int i = idx >> 6, j = idx & 63;
    float e = (i == j) ? 1.0f : 0.0f;
    T[idx] = e;
    Ms[idx] = e;
  }
  __syncthreads();
  for (int k = 1; k <= ORDERS; ++k) {
    float scale = t / (float)k;
    for (int r = 0; r < 16; ++r) {
      int idx = tid + 256 * r;
      int i = idx >> 6, j = idx & 63;
      float s = 0.f;
      #pragma unroll 16
      for (int l = 0; l < 64; ++l) s += Ah[i * 64 + l] * T[l * 64 + j];
      Tn[idx] = s * scale;
    }
    __syncthreads();
    for (int r = 0; r < 16; ++r) {
      int idx = tid + 256 * r;
      T[idx] = Tn[idx];
      Ms[idx] += Tn[idx];
    }
    __syncthreads();
  }
  for (int r = 0; r < 16; ++r) {
    int idx = tid + 256 * r;
    M_all[h * 4096 + idx] = Ms[idx];
  }
}

// -------- Kernel 2: W_eff[h*64+i][d] = sum_j M_h[i][j] W[h*64+j][d] (bf16) ----
__global__ void compute_weff_kernel(const float* __restrict__ W,
                                    const float* __restrict__ bvec,
                                    const float* __restrict__ M_all,
                                    unsigned short* __restrict__ Weff,
                                    float* __restrict__ beff) {
  __shared__ float Mh[64 * 64];
  __shared__ float Wc[64 * 256];
  const int h = blockIdx.y;
  const int chunk = blockIdx.x;
  const int tid = threadIdx.x;
  const int d = chunk * 256 + tid;
  for (int r = 0; r < 16; ++r) {
    int idx = tid + 256 * r;
    Mh[idx] = M_all[h * 4096 + idx];
  }
  for (int j = 0; j < 64; ++j)
    Wc[j * 256 + tid] = W[(size_t)(h * 64 + j) * 1024 + d];
  __syncthreads();
  for (int i = 0; i < 64; ++i) {
    float acc = 0.f;
    #pragma unroll 16
    for (int j = 0; j < 64; ++j) acc += Mh[i * 64 + j] * Wc[j * 256 + tid];
    Weff[(size_t)(h * 64 + i) * 1024 + d] = f32_to_bf16_rtn(acc);
  }
  if (chunk == 0 && tid < 64) {
    float acc = 0.f;
    for (int j = 0; j < 64; ++j) acc += Mh[tid * 64 + j] * bvec[h * 64 + j];
    beff[h * 64 + tid] = acc;
  }
}

// ---------------- Kernel 3: out = x @ W_eff^T + b_eff (bf16 MFMA) -------------
#define BM 128
#define BN 128
#define BK 64
#define LDSS 72  // padded stride in bf16 elements: 144 B, multiple of 16 B

__global__ __launch_bounds__(256, 2) void gemm_kernel(
    const float* __restrict__ X, const unsigned short* __restrict__ Weff,
    const float* __restrict__ beff, float* __restrict__ Out) {
  __shared__ unsigned short As[BM * LDSS];
  __shared__ unsigned short Bs[BN * LDSS];

  // XCD-aware bijective swizzle: 2048 blocks, 8 XCDs, N-fastest within chunk
  const int wg = blockIdx.x;
  const int swz = (wg & 7) * 256 + (wg >> 3);
  const int by = swz >> 3;  // 0..255 M-tile
  const int bx = swz & 7;   // 0..7   N-tile
  const int R = by * BM;
  const int C = bx * BN;

  const int tid = threadIdx.x;
  const int lane = tid & 63;
  const int wave = tid >> 6;
  const int wm = wave >> 1;  // 0..1
  const int wn = wave & 1;   // 0..1
  const int frow = lane & 15;
  const int fkg = lane >> 4;  // 0..3

  f32x4 acc[4][4];
  #pragma unroll
  for (int mi = 0; mi < 4; ++mi)
    #pragma unroll
    for (int ni = 0; ni < 4; ++ni) acc[mi][ni] = (f32x4){0.f, 0.f, 0.f, 0.f};

  for (int kt = 0; kt < 16; ++kt) {
    const int kbase = kt * BK;
    // A: 128x64 f32 -> 8 float4/thread
    float4 av[8];
    #pragma unroll
    for (int i = 0; i < 8; ++i) {
      int f = tid + 256 * i;
      int r = f >> 4;
      int kc = (f & 15) << 2;
      av[i] = *(const float4*)(X + (size_t)(R + r) * 1024 + kbase + kc);
    }
    // B: 128x64 bf16 -> 4 x 16B/thread
    uint4 bv[4];
    #pragma unroll
    for (int i = 0; i < 4; ++i) {
      int c = tid + 256 * i;
      int n = c >> 3;
      int kc = (c & 7) << 3;
      bv[i] = *(const uint4*)(Weff + (size_t)(C + n) * 1024 + kbase + kc);
    }
    __syncthreads();
    #pragma unroll
    for (int i = 0; i < 8; ++i) {
      int f = tid + 256 * i;
      int r = f >> 4;
      int kc = (f & 15) << 2;
      unsigned short tmp[4] = {f32_to_bf16_rtn(av[i].x), f32_to_bf16_rtn(av[i].y),
                               f32_to_bf16_rtn(av[i].z), f32_to_bf16_rtn(av[i].w)};
      *(uint2*)&As[r * LDSS + kc] = *(const uint2*)tmp;
    }
    #pragma unroll
    for (int i = 0; i < 4; ++i) {
      int c = tid + 256 * i;
      int n = c >> 3;
      int kc = (c & 7) << 3;
      *(uint4*)&Bs[n * LDSS + kc] = bv[i];
    }
    __syncthreads();

    short8 afr[4][2], bfr[4][2];
    #pragma unroll
    for (int mi = 0; mi < 4; ++mi)
      #pragma unroll
      for (int kk = 0; kk < 2; ++kk)
        afr[mi][kk] = *(const short8*)&As[(wm * 64 + mi * 16 + frow) * LDSS + kk * 32 + fkg * 8];
    #pragma unroll
    for (int ni = 0; ni < 4; ++ni)
      #pragma unroll
      for (int kk = 0; kk < 2; ++kk)
        bfr[ni][kk] = *(const short8*)&Bs[(wn * 64 + ni * 16 + frow) * LDSS + kk * 32 + fkg * 8];

    #pragma unroll
    for (int mi = 0; mi < 4; ++mi)
      #pragma unroll
      for (int ni = 0; ni < 4; ++ni)
        #pragma unroll
        for (int kk = 0; kk < 2; ++kk)
          acc[mi][ni] = __builtin_amdgcn_mfma_f32_16x16x32_bf16(
              afr[mi][kk], bfr[ni][kk], acc[mi][ni], 0, 0, 0);
  }

  // Epilogue: C/D layout col=lane&15, row=(lane>>4)*4+reg (m89-verified)
  #pragma unroll
  for (int ni = 0; ni < 4; ++ni) {
    int col = C + wn * 64 + ni * 16 + frow;
    float bias = beff[col];
    #pragma unroll
    for (int mi = 0; mi < 4; ++mi) {
      int row0 = R + wm * 64 + mi * 16 + fkg * 4;
      #pragma unroll
      for (int reg = 0; reg < 4; ++reg)
        Out[(size_t)(row0 + reg) * 1024 + col] = acc[mi][ni][reg] + bias;
    }
  }
}

extern "C" void kernel_launch(void* const* d_in, const int* in_sizes, int n_in,
                              void* d_out, int out_size, void* d_ws, size_t ws_size,
                              hipStream_t stream) {
  const float* x = (const float*)d_in[0];
  const float* t = (const float*)d_in[1];
  const float* W = (const float*)d_in[2];
  const float* b = (const float*)d_in[3];
  const float* A = (const float*)d_in[4];
  float* out = (float*)d_out;

  char* ws = (char*)d_ws;
  float* M_all = (float*)ws;                                   // 256 KB
  unsigned short* Weff = (unsigned short*)(ws + (256 << 10));  // 2 MB
  float* beff = (float*)(ws + (256 << 10) + (2 << 20));        // 4 KB

  compute_M_kernel<<<NHEAD, 256, 0, stream>>>(A, t, M_all);
  dim3 g2(4, NHEAD);
  compute_weff_kernel<<<g2, 256, 0, stream>>>(W, b, M_all, Weff, beff);
  gemm_kernel<<<2048, 256, 0, stream>>>(x, Weff, beff, out);
}

// Round 2
// 309.740 us; speedup vs baseline: 1.2549x; 1.2549x over previous
//
#include <hip/hip_runtime.h>
#include <hip/hip_bf16.h>
#include <cstdint>

#define NHEAD 16
#define HDIM 64
#define ORDERS 4

typedef short short8 __attribute__((ext_vector_type(8)));
typedef float f32x4 __attribute__((ext_vector_type(4)));

__device__ __forceinline__ unsigned short f32_to_bf16_rtn(float f) {
  union { float f; unsigned u; } v; v.f = f;
  unsigned r = v.u + 0x7FFFu + ((v.u >> 16) & 1u);
  return (unsigned short)(r >> 16);
}

// ---------------- Kernel 1: M_h = sum_{k=0..4} (t A_h)^k / k! ----------------
// 256 threads: thread owns row i = tid>>2, 16-col slice jq = (tid&3)*16.
// Ah padded to stride 65 (stride-64 f32 was a 16-way bank conflict).
__global__ void compute_M_kernel(const float* __restrict__ A,
                                 const float* __restrict__ t_ptr,
                                 float* __restrict__ M_all) {
  __shared__ float Ah[64 * 65];
  __shared__ float Tbuf0[64 * 64];
  __shared__ float Tbuf1[64 * 64];
  const int h = blockIdx.x;
  const int tid = threadIdx.x;
  const float t = t_ptr[0];
  const int i = tid >> 2;
  const int jq = (tid & 3) << 4;

  for (int r = 0; r < 16; ++r) {
    int idx = tid + 256 * r;
    Ah[(idx >> 6) * 65 + (idx & 63)] = A[h * 4096 + idx];
  }
  float ms[16];
  #pragma unroll
  for (int c = 0; c < 16; ++c) {
    float e = (i == jq + c) ? 1.0f : 0.0f;
    Tbuf0[i * 64 + jq + c] = e;
    ms[c] = e;
  }
  __syncthreads();

  float* Tc = Tbuf0;
  float* Tn = Tbuf1;
  for (int k = 1; k <= ORDERS; ++k) {
    float scale = t / (float)k;
    float acc[16];
    #pragma unroll
    for (int c = 0; c < 16; ++c) acc[c] = 0.f;
    for (int l = 0; l < 64; ++l) {
      float a = Ah[i * 65 + l];
      float4 t0 = *(const float4*)&Tc[l * 64 + jq];
      float4 t1 = *(const float4*)&Tc[l * 64 + jq + 4];
      float4 t2 = *(const float4*)&Tc[l * 64 + jq + 8];
      float4 t3 = *(const float4*)&Tc[l * 64 + jq + 12];
      acc[0] += a * t0.x;  acc[1] += a * t0.y;  acc[2] += a * t0.z;  acc[3] += a * t0.w;
      acc[4] += a * t1.x;  acc[5] += a * t1.y;  acc[6] += a * t1.z;  acc[7] += a * t1.w;
      acc[8] += a * t2.x;  acc[9] += a * t2.y;  acc[10] += a * t2.z; acc[11] += a * t2.w;
      acc[12] += a * t3.x; acc[13] += a * t3.y; acc[14] += a * t3.z; acc[15] += a * t3.w;
    }
    #pragma unroll
    for (int c = 0; c < 16; ++c) { acc[c] *= scale; ms[c] += acc[c]; }
    #pragma unroll
    for (int u = 0; u < 4; ++u) {
      float4 v = {acc[u * 4], acc[u * 4 + 1], acc[u * 4 + 2], acc[u * 4 + 3]};
      *(float4*)&Tn[i * 64 + jq + u * 4] = v;
    }
    __syncthreads();
    float* tmp = Tc; Tc = Tn; Tn = tmp;
  }
  #pragma unroll
  for (int u = 0; u < 4; ++u) {
    float4 v = {ms[u * 4], ms[u * 4 + 1], ms[u * 4 + 2], ms[u * 4 + 3]};
    *(float4*)&M_all[h * 4096 + i * 64 + jq + u * 4] = v;
  }
}

// -------- Kernel 2: W_eff[h*64+i][d] = sum_j M_h[i][j] W[h*64+j][d] (bf16) ----
__global__ void compute_weff_kernel(const float* __restrict__ W,
                                    const float* __restrict__ bvec,
                                    const float* __restrict__ M_all,
                                    unsigned short* __restrict__ Weff,
                                    float* __restrict__ beff) {
  __shared__ float Mh[64 * 64];
  __shared__ float Wc[64 * 256];
  const int h = blockIdx.y;
  const int chunk = blockIdx.x;
  const int tid = threadIdx.x;
  const int d = chunk * 256 + tid;
  for (int r = 0; r < 16; ++r) {
    int idx = tid + 256 * r;
    Mh[idx] = M_all[h * 4096 + idx];
  }
  for (int j = 0; j < 64; ++j)
    Wc[j * 256 + tid] = W[(size_t)(h * 64 + j) * 1024 + d];
  __syncthreads();
  for (int i = 0; i < 64; ++i) {
    float acc = 0.f;
    #pragma unroll 16
    for (int j = 0; j < 64; ++j) acc += Mh[i * 64 + j] * Wc[j * 256 + tid];
    Weff[(size_t)(h * 64 + i) * 1024 + d] = f32_to_bf16_rtn(acc);
  }
  if (chunk == 0 && tid < 64) {
    float acc = 0.f;
    for (int j = 0; j < 64; ++j) acc += Mh[tid * 64 + j] * bvec[h * 64 + j];
    beff[h * 64 + tid] = acc;
  }
}

// ---------------- Kernel 3: out = x @ W_eff^T + b_eff (bf16 MFMA) -------------
// Double-buffered LDS + reg-staged prefetch (T14): issue tile k+1 loads before
// MFMA of tile k; vmcnt wait lands after MFMAs; 1 barrier/iter.
// Epilogue stages C through LDS for full-line float4 stores (fixes 3.1x write amp).
#define BM 128
#define BN 128
#define BK 64
#define LDSS 72   // padded bf16 stride (144 B)
#define CSTR 136  // padded f32 stride for epilogue staging

__global__ __launch_bounds__(256, 2) void gemm_kernel(
    const float* __restrict__ X, const unsigned short* __restrict__ Weff,
    const float* __restrict__ beff, float* __restrict__ Out) {
  __shared__ __align__(16) unsigned short As0[BM * LDSS];
  __shared__ __align__(16) unsigned short As1[BM * LDSS];
  __shared__ __align__(16) unsigned short Bs0[BN * LDSS];
  __shared__ __align__(16) unsigned short Bs1[BN * LDSS];

  const int wg = blockIdx.x;
  const int swz = (wg & 7) * 256 + (wg >> 3);  // 2048 % 8 == 0: bijective
  const int by = swz >> 3;
  const int bx = swz & 7;
  const int R = by * BM;
  const int C = bx * BN;

  const int tid = threadIdx.x;
  const int lane = tid & 63;
  const int wave = tid >> 6;
  const int wm = wave >> 1;
  const int wn = wave & 1;
  const int frow = lane & 15;
  const int fkg = lane >> 4;

  f32x4 acc[4][4];
  #pragma unroll
  for (int mi = 0; mi < 4; ++mi)
    #pragma unroll
    for (int ni = 0; ni < 4; ++ni) acc[mi][ni] = (f32x4){0.f, 0.f, 0.f, 0.f};

  // Per-thread staging geometry
  const int ar = tid >> 4;            // A row (+16 per chunk)
  const int akc = (tid & 15) << 2;    // A k-offset (floats)
  const int bn_ = tid >> 3;           // B row (+32 per chunk)
  const int bkc = (tid & 7) << 3;     // B k-offset (bf16)
  const float* Xbase = X + (size_t)(R + ar) * 1024 + akc;
  const unsigned short* Wbase = Weff + (size_t)(C + bn_) * 1024 + bkc;

  float4 av[8];
  uint4 bv[4];

  auto loadTile = [&](int kt) {
    const int kb = kt * BK;
    #pragma unroll
    for (int i = 0; i < 8; ++i)
      av[i] = *(const float4*)(Xbase + (size_t)i * 16 * 1024 + kb);
    #pragma unroll
    for (int i = 0; i < 4; ++i)
      bv[i] = *(const uint4*)(Wbase + (size_t)i * 32 * 1024 + kb);
  };
  auto writeTile = [&](unsigned short* Asn, unsigned short* Bsn) {
    #pragma unroll
    for (int i = 0; i < 8; ++i) {
      unsigned short tmp[4] = {f32_to_bf16_rtn(av[i].x), f32_to_bf16_rtn(av[i].y),
                               f32_to_bf16_rtn(av[i].z), f32_to_bf16_rtn(av[i].w)};
      *(uint2*)&Asn[(ar + i * 16) * LDSS + akc] = *(const uint2*)tmp;
    }
    #pragma unroll
    for (int i = 0; i < 4; ++i)
      *(uint4*)&Bsn[(bn_ + i * 32) * LDSS + bkc] = bv[i];
  };

  // Prologue: tile 0
  loadTile(0);
  writeTile(As0, Bs0);
  __syncthreads();

  unsigned short* Asc = As0; unsigned short* Asn = As1;
  unsigned short* Bsc = Bs0; unsigned short* Bsn = Bs1;

  for (int kt = 0; kt < 16; ++kt) {
    if (kt < 15) loadTile(kt + 1);  // issue early: overlaps MFMA below

    short8 afr[4][2], bfr[4][2];
    #pragma unroll
    for (int mi = 0; mi < 4; ++mi)
      #pragma unroll
      for (int kk = 0; kk < 2; ++kk)
        afr[mi][kk] = *(const short8*)&Asc[(wm * 64 + mi * 16 + frow) * LDSS + kk * 32 + fkg * 8];
    #pragma unroll
    for (int ni = 0; ni < 4; ++ni)
      #pragma unroll
      for (int kk = 0; kk < 2; ++kk)
        bfr[ni][kk] = *(const short8*)&Bsc[(wn * 64 + ni * 16 + frow) * LDSS + kk * 32 + fkg * 8];
    #pragma unroll
    for (int mi = 0; mi < 4; ++mi)
      #pragma unroll
      for (int ni = 0; ni < 4; ++ni)
        #pragma unroll
        for (int kk = 0; kk < 2; ++kk)
          acc[mi][ni] = __builtin_amdgcn_mfma_f32_16x16x32_bf16(
              afr[mi][kk], bfr[ni][kk], acc[mi][ni], 0, 0, 0);

    if (kt < 15) writeTile(Asn, Bsn);  // vmcnt wait lands here, after MFMAs
    __syncthreads();
    unsigned short* t1 = Asc; Asc = Asn; Asn = t1;
    unsigned short* t2 = Bsc; Bsc = Bsn; Bsn = t2;
  }

  // Epilogue: stage 32x128 f32 through LDS per mi, store full-line float4 rows.
  float* Cs = (float*)As0;  // 32*136*4 = 17408 B < 18432 B
  const int c4 = (tid & 31) << 2;
  float4 bb = *(const float4*)&beff[C + c4];
  #pragma unroll
  for (int mi = 0; mi < 4; ++mi) {
    #pragma unroll
    for (int ni = 0; ni < 4; ++ni) {
      int col = wn * 64 + ni * 16 + frow;
      #pragma unroll
      for (int reg = 0; reg < 4; ++reg)
        Cs[(wm * 16 + fkg * 4 + reg) * CSTR + col] = acc[mi][ni][reg];
    }
    __syncthreads();
    #pragma unroll
    for (int it = 0; it < 4; ++it) {
      int rloc = it * 8 + (tid >> 5);
      float4 v = *(const float4*)&Cs[rloc * CSTR + c4];
      v.x += bb.x; v.y += bb.y; v.z += bb.z; v.w += bb.w;
      int grow = R + (rloc >> 4) * 64 + mi * 16 + (rloc & 15);
      *(float4*)(Out + (size_t)grow * 1024 + C + c4) = v;
    }
    __syncthreads();
  }
}

extern "C" void kernel_launch(void* const* d_in, const int* in_sizes, int n_in,
                              void* d_out, int out_size, void* d_ws, size_t ws_size,
                              hipStream_t stream) {
  const float* x = (const float*)d_in[0];
  const float* t = (const float*)d_in[1];
  const float* W = (const float*)d_in[2];
  const float* b = (const float*)d_in[3];
  const float* A = (const float*)d_in[4];
  float* out = (float*)d_out;

  char* ws = (char*)d_ws;
  float* M_all = (float*)ws;                                   // 256 KB
  unsigned short* Weff = (unsigned short*)(ws + (256 << 10));  // 2 MB
  float* beff = (float*)(ws + (256 << 10) + (2 << 20));        // 4 KB

  compute_M_kernel<<<NHEAD, 256, 0, stream>>>(A, t, M_all);
  dim3 g2(4, NHEAD);
  compute_weff_kernel<<<g2, 256, 0, stream>>>(W, b, M_all, Weff, beff);
  gemm_kernel<<<2048, 256, 0, stream>>>(x, Weff, beff, out);
}

// Round 3
// 188.733 us; speedup vs baseline: 2.0595x; 1.6412x over previous
//
#include <hip/hip_runtime.h>
#include <hip/hip_bf16.h>
#include <cstdint>

#define NHEAD 16
#define ORDERS 4

typedef short short8 __attribute__((ext_vector_type(8)));
typedef float f32x4 __attribute__((ext_vector_type(4)));

__device__ __forceinline__ unsigned short f32_to_bf16_rtn(float f) {
  union { float f; unsigned u; } v; v.f = f;
  unsigned r = v.u + 0x7FFFu + ((v.u >> 16) & 1u);
  return (unsigned short)(r >> 16);
}

typedef __attribute__((address_space(1))) void gvoid;
typedef __attribute__((address_space(3))) void svoid;
__device__ __forceinline__ void gload_lds16(const void* g, void* l) {
  // dest = lds_base + lane*16 (wave-uniform base); src is per-lane
  __builtin_amdgcn_global_load_lds((gvoid*)g, (svoid*)l, 16, 0, 0);
}

// ---------------- Kernel 1: M_h = sum_{k=0..4} (t A_h)^k / k! ----------------
__global__ void compute_M_kernel(const float* __restrict__ A,
                                 const float* __restrict__ t_ptr,
                                 float* __restrict__ M_all) {
  __shared__ float Ah[64 * 65];
  __shared__ float Tbuf0[64 * 64];
  __shared__ float Tbuf1[64 * 64];
  const int h = blockIdx.x;
  const int tid = threadIdx.x;
  const float t = t_ptr[0];
  const int i = tid >> 2;
  const int jq = (tid & 3) << 4;

  for (int r = 0; r < 16; ++r) {
    int idx = tid + 256 * r;
    Ah[(idx >> 6) * 65 + (idx & 63)] = A[h * 4096 + idx];
  }
  float ms[16];
  #pragma unroll
  for (int c = 0; c < 16; ++c) {
    float e = (i == jq + c) ? 1.0f : 0.0f;
    Tbuf0[i * 64 + jq + c] = e;
    ms[c] = e;
  }
  __syncthreads();

  float* Tc = Tbuf0;
  float* Tn = Tbuf1;
  for (int k = 1; k <= ORDERS; ++k) {
    float scale = t / (float)k;
    float acc[16];
    #pragma unroll
    for (int c = 0; c < 16; ++c) acc[c] = 0.f;
    for (int l = 0; l < 64; ++l) {
      float a = Ah[i * 65 + l];
      float4 t0 = *(const float4*)&Tc[l * 64 + jq];
      float4 t1 = *(const float4*)&Tc[l * 64 + jq + 4];
      float4 t2 = *(const float4*)&Tc[l * 64 + jq + 8];
      float4 t3 = *(const float4*)&Tc[l * 64 + jq + 12];
      acc[0] += a * t0.x;  acc[1] += a * t0.y;  acc[2] += a * t0.z;  acc[3] += a * t0.w;
      acc[4] += a * t1.x;  acc[5] += a * t1.y;  acc[6] += a * t1.z;  acc[7] += a * t1.w;
      acc[8] += a * t2.x;  acc[9] += a * t2.y;  acc[10] += a * t2.z; acc[11] += a * t2.w;
      acc[12] += a * t3.x; acc[13] += a * t3.y; acc[14] += a * t3.z; acc[15] += a * t3.w;
    }
    #pragma unroll
    for (int c = 0; c < 16; ++c) { acc[c] *= scale; ms[c] += acc[c]; }
    #pragma unroll
    for (int u = 0; u < 4; ++u) {
      float4 v = {acc[u * 4], acc[u * 4 + 1], acc[u * 4 + 2], acc[u * 4 + 3]};
      *(float4*)&Tn[i * 64 + jq + u * 4] = v;
    }
    __syncthreads();
    float* tmp = Tc; Tc = Tn; Tn = tmp;
  }
  #pragma unroll
  for (int u = 0; u < 4; ++u) {
    float4 v = {ms[u * 4], ms[u * 4 + 1], ms[u * 4 + 2], ms[u * 4 + 3]};
    *(float4*)&M_all[h * 4096 + i * 64 + jq + u * 4] = v;
  }
}

// -------- Kernel 2: W_eff[h*64+i][d] = sum_j M_h[i][j] W[h*64+j][d] (bf16) ----
__global__ void compute_weff_kernel(const float* __restrict__ W,
                                    const float* __restrict__ bvec,
                                    const float* __restrict__ M_all,
                                    unsigned short* __restrict__ Weff,
                                    float* __restrict__ beff) {
  __shared__ float Mh[64 * 64];
  __shared__ float Wc[64 * 256];
  const int h = blockIdx.y;
  const int chunk = blockIdx.x;
  const int tid = threadIdx.x;
  const int d = chunk * 256 + tid;
  for (int r = 0; r < 16; ++r) {
    int idx = tid + 256 * r;
    Mh[idx] = M_all[h * 4096 + idx];
  }
  for (int j = 0; j < 64; ++j)
    Wc[j * 256 + tid] = W[(size_t)(h * 64 + j) * 1024 + d];
  __syncthreads();
  for (int i = 0; i < 64; ++i) {
    float acc = 0.f;
    #pragma unroll 16
    for (int j = 0; j < 64; ++j) acc += Mh[i * 64 + j] * Wc[j * 256 + tid];
    Weff[(size_t)(h * 64 + i) * 1024 + d] = f32_to_bf16_rtn(acc);
  }
  if (chunk == 0 && tid < 64) {
    float acc = 0.f;
    for (int j = 0; j < 64; ++j) acc += Mh[tid * 64 + j] * bvec[h * 64 + j];
    beff[h * 64 + tid] = acc;
  }
}

// ---------------- Prepass: X f32 -> bf16 (RTN), 192 MB BW-bound --------------
__global__ void convert_x_kernel(const float* __restrict__ X,
                                 unsigned short* __restrict__ Xb, int n8) {
  int idx = blockIdx.x * blockDim.x + threadIdx.x;
  int stride = gridDim.x * blockDim.x;
  for (int i = idx; i < n8; i += stride) {
    float4 a = *(const float4*)(X + (size_t)i * 8);
    float4 b = *(const float4*)(X + (size_t)i * 8 + 4);
    unsigned short t[8] = {f32_to_bf16_rtn(a.x), f32_to_bf16_rtn(a.y),
                           f32_to_bf16_rtn(a.z), f32_to_bf16_rtn(a.w),
                           f32_to_bf16_rtn(b.x), f32_to_bf16_rtn(b.y),
                           f32_to_bf16_rtn(b.z), f32_to_bf16_rtn(b.w)};
    *(uint4*)(Xb + (size_t)i * 8) = *(const uint4*)t;
  }
}

// ------------- Kernel 3 (m97 structure): out = Xb @ Weff^T + beff ------------
// 128x128x64 tile, 4 waves, single-buffered 32KB LDS, global_load_lds width 16
// for BOTH operands (no VGPR roundtrip, no VALU in staging), 2 barriers/K-step.
#define CSTR 132  // padded f32 stride for epilogue staging

__global__ __launch_bounds__(256, 3) void gemm_kernel(
    const unsigned short* __restrict__ Xb, const unsigned short* __restrict__ Wf,
    const float* __restrict__ beff, float* __restrict__ Out) {
  __shared__ __align__(16) unsigned short smem[2 * 128 * 64];  // 32 KB
  unsigned short* As = smem;
  unsigned short* Bs = smem + 128 * 64;

  const int wg = blockIdx.x;
  const int swz = (wg & 7) * 256 + (wg >> 3);  // 2048 % 8 == 0: bijective
  const int by = swz >> 3;
  const int bx = swz & 7;
  const int R = by * 128;
  const int C = bx * 128;

  const int tid = threadIdx.x;
  const int lane = tid & 63;
  const int wave = tid >> 6;
  const int wm = wave >> 1;
  const int wn = wave & 1;
  const int frow = lane & 15;
  const int fkg = lane >> 4;

  f32x4 acc[4][4];
  #pragma unroll
  for (int mi = 0; mi < 4; ++mi)
    #pragma unroll
    for (int ni = 0; ni < 4; ++ni) acc[mi][ni] = (f32x4){0.f, 0.f, 0.f, 0.f};

  // Staging geometry: chunk c = wave*4+i covers tile rows [c*8, c*8+8);
  // lane supplies row c*8+(lane>>3), 16B slot (lane&7). LDS stays linear.
  const int arow = wave * 32 + (lane >> 3);
  const int acol = (lane & 7) << 3;
  const unsigned short* Asrc = Xb + (size_t)(R + arow) * 1024 + acol;
  const unsigned short* Bsrc = Wf + (size_t)(C + arow) * 1024 + acol;
  char* AsDst = (char*)As + wave * 4096;
  char* BsDst = (char*)Bs + wave * 4096;

  for (int kt = 0; kt < 16; ++kt) {
    if (kt) __syncthreads();  // all waves done reading previous tile
    const int kb = kt * 64;
    #pragma unroll
    for (int i = 0; i < 4; ++i)
      gload_lds16(Asrc + (size_t)i * 8 * 1024 + kb, AsDst + i * 1024);
    #pragma unroll
    for (int i = 0; i < 4; ++i)
      gload_lds16(Bsrc + (size_t)i * 8 * 1024 + kb, BsDst + i * 1024);
    __syncthreads();  // compiler emits vmcnt(0) drain before barrier

    short8 afr[4][2], bfr[4][2];
    #pragma unroll
    for (int mi = 0; mi < 4; ++mi)
      #pragma unroll
      for (int kk = 0; kk < 2; ++kk)
        afr[mi][kk] = *(const short8*)&As[(wm * 64 + mi * 16 + frow) * 64 + kk * 32 + fkg * 8];
    #pragma unroll
    for (int ni = 0; ni < 4; ++ni)
      #pragma unroll
      for (int kk = 0; kk < 2; ++kk)
        bfr[ni][kk] = *(const short8*)&Bs[(wn * 64 + ni * 16 + frow) * 64 + kk * 32 + fkg * 8];
    #pragma unroll
    for (int mi = 0; mi < 4; ++mi)
      #pragma unroll
      for (int ni = 0; ni < 4; ++ni)
        #pragma unroll
        for (int kk = 0; kk < 2; ++kk)
          acc[mi][ni] = __builtin_amdgcn_mfma_f32_16x16x32_bf16(
              afr[mi][kk], bfr[ni][kk], acc[mi][ni], 0, 0, 0);
  }
  __syncthreads();

  // Epilogue: stage 32x128 f32 tile through LDS -> full-line float4 stores
  float* Cs = (float*)smem;  // 32*132*4 = 16896 B <= 32 KB
  const int c4 = (tid & 31) << 2;
  float4 bb = *(const float4*)&beff[C + c4];
  #pragma unroll
  for (int mi = 0; mi < 4; ++mi) {
    #pragma unroll
    for (int ni = 0; ni < 4; ++ni) {
      int col = wn * 64 + ni * 16 + frow;
      #pragma unroll
      for (int reg = 0; reg < 4; ++reg)
        Cs[(wm * 16 + fkg * 4 + reg) * CSTR + col] = acc[mi][ni][reg];
    }
    __syncthreads();
    #pragma unroll
    for (int it = 0; it < 4; ++it) {
      int rloc = it * 8 + (tid >> 5);
      float4 v = *(const float4*)&Cs[rloc * CSTR + c4];
      v.x += bb.x; v.y += bb.y; v.z += bb.z; v.w += bb.w;
      int grow = R + (rloc >> 4) * 64 + mi * 16 + (rloc & 15);
      *(float4*)(Out + (size_t)grow * 1024 + C + c4) = v;
    }
    __syncthreads();
  }
}

// ---------------- Fallback GEMM (reg-staged, f32 X) if ws is small -----------
#define LDSS 72
#define CSTRF 136
__global__ __launch_bounds__(256, 2) void gemm_fb(
    const float* __restrict__ X, const unsigned short* __restrict__ Weff,
    const float* __restrict__ beff, float* __restrict__ Out) {
  __shared__ __align__(16) unsigned short As0[128 * LDSS];
  __shared__ __align__(16) unsigned short As1[128 * LDSS];
  __shared__ __align__(16) unsigned short Bs0[128 * LDSS];
  __shared__ __align__(16) unsigned short Bs1[128 * LDSS];
  const int wg = blockIdx.x;
  const int swz = (wg & 7) * 256 + (wg >> 3);
  const int R = (swz >> 3) * 128;
  const int C = (swz & 7) * 128;
  const int tid = threadIdx.x;
  const int lane = tid & 63;
  const int wave = tid >> 6;
  const int wm = wave >> 1, wn = wave & 1;
  const int frow = lane & 15, fkg = lane >> 4;
  f32x4 acc[4][4];
  #pragma unroll
  for (int mi = 0; mi < 4; ++mi)
    #pragma unroll
    for (int ni = 0; ni < 4; ++ni) acc[mi][ni] = (f32x4){0.f, 0.f, 0.f, 0.f};
  const int ar = tid >> 4, akc = (tid & 15) << 2;
  const int bn_ = tid >> 3, bkc = (tid & 7) << 3;
  const float* Xbase = X + (size_t)(R + ar) * 1024 + akc;
  const unsigned short* Wbase = Weff + (size_t)(C + bn_) * 1024 + bkc;
  float4 av[8];
  uint4 bv[4];
  auto loadTile = [&](int kt) {
    const int kb = kt * 64;
    #pragma unroll
    for (int i = 0; i < 8; ++i) av[i] = *(const float4*)(Xbase + (size_t)i * 16 * 1024 + kb);
    #pragma unroll
    for (int i = 0; i < 4; ++i) bv[i] = *(const uint4*)(Wbase + (size_t)i * 32 * 1024 + kb);
  };
  auto writeTile = [&](unsigned short* Asn, unsigned short* Bsn) {
    #pragma unroll
    for (int i = 0; i < 8; ++i) {
      unsigned short tmp[4] = {f32_to_bf16_rtn(av[i].x), f32_to_bf16_rtn(av[i].y),
                               f32_to_bf16_rtn(av[i].z), f32_to_bf16_rtn(av[i].w)};
      *(uint2*)&Asn[(ar + i * 16) * LDSS + akc] = *(const uint2*)tmp;
    }
    #pragma unroll
    for (int i = 0; i < 4; ++i) *(uint4*)&Bsn[(bn_ + i * 32) * LDSS + bkc] = bv[i];
  };
  loadTile(0);
  writeTile(As0, Bs0);
  __syncthreads();
  unsigned short* Asc = As0; unsigned short* Asn = As1;
  unsigned short* Bsc = Bs0; unsigned short* Bsn = Bs1;
  for (int kt = 0; kt < 16; ++kt) {
    if (kt < 15) loadTile(kt + 1);
    short8 afr[4][2], bfr[4][2];
    #pragma unroll
    for (int mi = 0; mi < 4; ++mi)
      #pragma unroll
      for (int kk = 0; kk < 2; ++kk)
        afr[mi][kk] = *(const short8*)&Asc[(wm * 64 + mi * 16 + frow) * LDSS + kk * 32 + fkg * 8];
    #pragma unroll
    for (int ni = 0; ni < 4; ++ni)
      #pragma unroll
      for (int kk = 0; kk < 2; ++kk)
        bfr[ni][kk] = *(const short8*)&Bsc[(wn * 64 + ni * 16 + frow) * LDSS + kk * 32 + fkg * 8];
    #pragma unroll
    for (int mi = 0; mi < 4; ++mi)
      #pragma unroll
      for (int ni = 0; ni < 4; ++ni)
        #pragma unroll
        for (int kk = 0; kk < 2; ++kk)
          acc[mi][ni] = __builtin_amdgcn_mfma_f32_16x16x32_bf16(
              afr[mi][kk], bfr[ni][kk], acc[mi][ni], 0, 0, 0);
    if (kt < 15) writeTile(Asn, Bsn);
    __syncthreads();
    unsigned short* t1 = Asc; Asc = Asn; Asn = t1;
    unsigned short* t2 = Bsc; Bsc = Bsn; Bsn = t2;
  }
  float* Cs = (float*)As0;
  const int c4 = (tid & 31) << 2;
  float4 bb = *(const float4*)&beff[C + c4];
  #pragma unroll
  for (int mi = 0; mi < 4; ++mi) {
    #pragma unroll
    for (int ni = 0; ni < 4; ++ni) {
      int col = wn * 64 + ni * 16 + frow;
      #pragma unroll
      for (int reg = 0; reg < 4; ++reg)
        Cs[(wm * 16 + fkg * 4 + reg) * CSTRF + col] = acc[mi][ni][reg];
    }
    __syncthreads();
    #pragma unroll
    for (int it = 0; it < 4; ++it) {
      int rloc = it * 8 + (tid >> 5);
      float4 v = *(const float4*)&Cs[rloc * CSTRF + c4];
      v.x += bb.x; v.y += bb.y; v.z += bb.z; v.w += bb.w;
      int grow = R + (rloc >> 4) * 64 + mi * 16 + (rloc & 15);
      *(float4*)(Out + (size_t)grow * 1024 + C + c4) = v;
    }
    __syncthreads();
  }
}

extern "C" void kernel_launch(void* const* d_in, const int* in_sizes, int n_in,
                              void* d_out, int out_size, void* d_ws, size_t ws_size,
                              hipStream_t stream) {
  const float* x = (const float*)d_in[0];
  const float* t = (const float*)d_in[1];
  const float* W = (const float*)d_in[2];
  const float* b = (const float*)d_in[3];
  const float* A = (const float*)d_in[4];
  float* out = (float*)d_out;

  char* ws = (char*)d_ws;
  float* M_all = (float*)ws;                                   // 256 KB @ 0
  unsigned short* Weff = (unsigned short*)(ws + (256 << 10));  // 2 MB
  float* beff = (float*)(ws + (256 << 10) + (2 << 20));        // 4 KB
  unsigned short* Xb = (unsigned short*)(ws + (4ull << 20));   // 64 MB @ 4 MB

  compute_M_kernel<<<NHEAD, 256, 0, stream>>>(A, t, M_all);
  dim3 g2(4, NHEAD);
  compute_weff_kernel<<<g2, 256, 0, stream>>>(W, b, M_all, Weff, beff);

  const size_t need = (4ull << 20) + (64ull << 20);
  if (ws_size >= need) {
    convert_x_kernel<<<2048, 256, 0, stream>>>(x, Xb, 33554432 / 8);
    gemm_kernel<<<2048, 256, 0, stream>>>(Xb, Weff, beff, out);
  } else {
    gemm_fb<<<2048, 256, 0, stream>>>(x, Weff, beff, out);
  }
}